// Round 3
// baseline (198.369 us; speedup 1.0000x reference)
//
#include <hip/hip_runtime.h>
#include <hip/hip_bf16.h>
#include <stdint.h>

#define BB 2048
#define UU 1024
#define SKIPN 24

typedef __attribute__((ext_vector_type(8))) short short8;
typedef __attribute__((ext_vector_type(4))) float f32x4;
typedef __attribute__((ext_vector_type(4))) unsigned short ushort4_t;

static __device__ __forceinline__ float sigmoidf_(float x) {
    return 1.0f / (1.0f + __expf(-x));
}

static __device__ __forceinline__ void load_lds16(const void* g, void* l) {
    __builtin_amdgcn_global_load_lds((const __attribute__((address_space(1))) void*)g,
                                     (__attribute__((address_space(3))) void*)l, 16, 0, 0);
}

// ---------------- prep: weight transpose->bf16 + activation convert->bf16 -------
// blocks [0,9216): transpose; [9216,21504): convert
__global__ __launch_bounds__(256) void prep(
    const float* __restrict__ inputs, const float* __restrict__ h_tm1,
    const float* __restrict__ prev_h, const float* __restrict__ kernel,
    const float* __restrict__ rkernel, const float* __restrict__ kernel2,
    __hip_bfloat16* __restrict__ kt, __hip_bfloat16* __restrict__ rkt,
    __hip_bfloat16* __restrict__ k2t, __hip_bfloat16* __restrict__ xin,
    __hip_bfloat16* __restrict__ hb, __hip_bfloat16* __restrict__ ph0) {
    const int bid = blockIdx.x;
    if (bid < 9216) {
        __shared__ float tile[32][33];
        const float* src;
        __hip_bfloat16* dst;
        int C, local;
        if (bid < 4096)      { src = kernel;  dst = kt;  C = 4096; local = bid; }
        else if (bid < 8192) { src = rkernel; dst = rkt; C = 4096; local = bid - 4096; }
        else                 { src = kernel2; dst = k2t; C = 1024; local = bid - 8192; }
        const int xt = (C == 4096) ? 128 : 32;
        const int bc = (local % xt) * 32;
        const int br = (local / xt) * 32;
        const int tx = threadIdx.x & 31, ty = threadIdx.x >> 5;
#pragma unroll
        for (int i = 0; i < 32; i += 8)
            tile[ty + i][tx] = src[(size_t)(br + ty + i) * C + bc + tx];
        __syncthreads();
#pragma unroll
        for (int i = 0; i < 32; i += 8)
            dst[(size_t)(bc + ty + i) * 1024 + br + tx] = __float2bfloat16(tile[tx][ty + i]);
    } else {
        const int idx = (bid - 9216) * 256 + threadIdx.x;  // float4 index
        const float* src;
        __hip_bfloat16* dst;
        int off;
        if (idx < 524288) { dst = xin; off = idx; src = inputs + (size_t)off * 4; }
        else if (idx < 2621440) { off = idx - 524288; dst = hb; src = h_tm1 + (size_t)off * 4; }
        else {
            const int i = idx - 2621440;
            const int b = i >> 8, c4 = i & 255;
            off = i; dst = ph0;
            src = prev_h + (size_t)b * (UU * SKIPN) + c4 * 4;
        }
        const float4 v = *(const float4*)src;
        union { __hip_bfloat16 h[4]; ushort4_t u; } cv;
        cv.h[0] = __float2bfloat16(v.x);
        cv.h[1] = __float2bfloat16(v.y);
        cv.h[2] = __float2bfloat16(v.z);
        cv.h[3] = __float2bfloat16(v.w);
        *(ushort4_t*)(dst + (size_t)off * 4) = cv.u;
    }
}

// ---------------- mega: fused 5-gate GEMM+epilogue blocks  ||  prev_h copy blocks
// do_copy=1: grid 256, even bids = gemm (g=bid>>1), odd = copy (cb=bid>>1)
// do_copy=0: grid 128, all gemm (g=bid); no out_prev tail write (scratch aliases)
__global__ __launch_bounds__(512) void mega(
    const __hip_bfloat16* __restrict__ xin, const __hip_bfloat16* __restrict__ hb,
    const __hip_bfloat16* __restrict__ ph0, const __hip_bfloat16* __restrict__ kt,
    const __hip_bfloat16* __restrict__ rkt, const __hip_bfloat16* __restrict__ k2t,
    const float* __restrict__ c_tm1, const float* __restrict__ bias,
    const float* __restrict__ bias2, const float* __restrict__ s0p,
    const float* __restrict__ prev_h, const float* __restrict__ step,
    float* __restrict__ out_h, float* __restrict__ out_ht, float* __restrict__ out_c,
    float* __restrict__ out_step, float* __restrict__ out_prev, int do_copy) {
    const int bid = blockIdx.x;
    if (do_copy && (bid & 1)) {
        // ---- copy role: shift prev_h[:, 1024:] -> out_prev[:, :23552) ----
        const int cb = bid >> 1;  // 0..127
        for (int r = 0; r < 16; ++r) {
            const int b = cb * 16 + r;
            const float4* s = (const float4*)(prev_h + (size_t)b * 24576 + 1024);
            float4* d = (float4*)(out_prev + (size_t)b * 24576);
            for (int c = threadIdx.x; c < 5888; c += 512) d[c] = s[c];
        }
        if (cb == 0)
            for (int i = threadIdx.x; i < 2048; i += 512) out_step[i] = step[i] + 1.0f;
        return;
    }
    const int g = do_copy ? (bid >> 1) : bid;  // 0..127
    const int v0 = (g & 7) * 128;   // unit-col tile
    const int b0 = (g >> 3) * 128;  // batch-row tile

    __shared__ char As[2 * 32768];  // [buf][4 tiles][128*32 bf16]
    __shared__ char Bs[2 * 32768];
#define ATILE(buf, t) (As + (buf) * 32768 + (t) * 8192)
#define BTILE(buf, t) (Bs + (buf) * 32768 + (t) * 8192)

    const int tid = threadIdx.x;
    const int lane = tid & 63;
    const int wid = tid >> 6;       // 0..7
    const int wrow = wid >> 2;      // 0..1  (x64 rows)
    const int wcol = wid & 3;       // 0..3  (x32 cols)
    const int srow = tid >> 2;      // 0..127 staging row
    const int sslot = tid & 3;
    const int kofs = ((sslot ^ (srow & 3)) << 3);  // swizzled src k-offset (elems)
    const int l15 = lane & 15, hi = lane >> 4;
    const int rswB = ((hi ^ (l15 & 3)) << 4);      // swizzled LDS read offset (bytes)
    const int ldst = wid * 1024;                   // wave-uniform LDS dest offset

    f32x4 acc[5][4][2];
#pragma unroll
    for (int q = 0; q < 5; q++)
#pragma unroll
        for (int m = 0; m < 4; m++)
#pragma unroll
            for (int n = 0; n < 2; n++) acc[q][m][n] = (f32x4){0.f, 0.f, 0.f, 0.f};

#define BARRIER() asm volatile("s_barrier" ::: "memory")
#define WAITV(N) asm volatile("s_waitcnt vmcnt(" #N ")" ::: "memory")
#define WAITL0() asm volatile("s_waitcnt lgkmcnt(0)" ::: "memory")

    // ---------------- Panel X: x @ kt_g, 4 gates batched (K=1024) ----------------
    {
        const __hip_bfloat16* Ar = xin + (size_t)(b0 + srow) * 1024 + kofs;
        const __hip_bfloat16* Wr = kt + (size_t)(v0 + srow) * 1024 + kofs;
        load_lds16(Ar, ATILE(0, 0) + ldst);
#pragma unroll
        for (int gg = 0; gg < 4; ++gg)
            load_lds16(Wr + (size_t)gg * 1048576, BTILE(0, gg) + ldst);
#pragma unroll 2
        for (int it = 0; it < 32; ++it) {
            const int cur = it & 1, k0 = it * 32;
            if (it < 31) {
                load_lds16(Ar + k0 + 32, ATILE(cur ^ 1, 0) + ldst);
#pragma unroll
                for (int gg = 0; gg < 4; ++gg)
                    load_lds16(Wr + (size_t)gg * 1048576 + k0 + 32, BTILE(cur ^ 1, gg) + ldst);
                WAITV(5);
            } else {
                WAITV(0);
            }
            BARRIER();
            short8 af[4];
#pragma unroll
            for (int m = 0; m < 4; ++m)
                af[m] = *(const short8*)(ATILE(cur, 0) + (wrow * 64 + m * 16 + l15) * 64 + rswB);
#pragma unroll
            for (int gg = 0; gg < 4; ++gg) {
                short8 bq0 = *(const short8*)(BTILE(cur, gg) + (wcol * 32 + l15) * 64 + rswB);
                short8 bq1 = *(const short8*)(BTILE(cur, gg) + (wcol * 32 + 16 + l15) * 64 + rswB);
#pragma unroll
                for (int m = 0; m < 4; ++m) {
                    acc[gg][m][0] = __builtin_amdgcn_mfma_f32_16x16x32_bf16(af[m], bq0, acc[gg][m][0], 0, 0, 0);
                    acc[gg][m][1] = __builtin_amdgcn_mfma_f32_16x16x32_bf16(af[m], bq1, acc[gg][m][1], 0, 0, 0);
                }
            }
            WAITL0();
            BARRIER();
        }
    }
    // ---------------- Panel H: h_g @ rkt_g, 4 gates batched (K=1024) -------------
    {
        const __hip_bfloat16* Hr = hb + (size_t)(b0 + srow) * 4096 + kofs;
        const __hip_bfloat16* Rr = rkt + (size_t)(v0 + srow) * 1024 + kofs;
#pragma unroll
        for (int gg = 0; gg < 4; ++gg) {
            load_lds16(Hr + gg * 1024, ATILE(0, gg) + ldst);
            load_lds16(Rr + (size_t)gg * 1048576, BTILE(0, gg) + ldst);
        }
#pragma unroll 2
        for (int it = 0; it < 32; ++it) {
            const int cur = it & 1, k0 = it * 32;
            if (it < 31) {
#pragma unroll
                for (int gg = 0; gg < 4; ++gg) {
                    load_lds16(Hr + gg * 1024 + k0 + 32, ATILE(cur ^ 1, gg) + ldst);
                    load_lds16(Rr + (size_t)gg * 1048576 + k0 + 32, BTILE(cur ^ 1, gg) + ldst);
                }
                WAITV(8);
            } else {
                WAITV(0);
            }
            BARRIER();
#pragma unroll
            for (int gg = 0; gg < 4; ++gg) {
                short8 bq0 = *(const short8*)(BTILE(cur, gg) + (wcol * 32 + l15) * 64 + rswB);
                short8 bq1 = *(const short8*)(BTILE(cur, gg) + (wcol * 32 + 16 + l15) * 64 + rswB);
#pragma unroll
                for (int m = 0; m < 4; ++m) {
                    short8 am = *(const short8*)(ATILE(cur, gg) + (wrow * 64 + m * 16 + l15) * 64 + rswB);
                    acc[gg][m][0] = __builtin_amdgcn_mfma_f32_16x16x32_bf16(am, bq0, acc[gg][m][0], 0, 0, 0);
                    acc[gg][m][1] = __builtin_amdgcn_mfma_f32_16x16x32_bf16(am, bq1, acc[gg][m][1], 0, 0, 0);
                }
            }
            WAITL0();
            BARRIER();
        }
    }
    // ---------------- Panel S: ph0 @ k2t (K=1024) --------------------------------
    {
        const __hip_bfloat16* Pr = ph0 + (size_t)(b0 + srow) * 1024 + kofs;
        const __hip_bfloat16* Kr = k2t + (size_t)(v0 + srow) * 1024 + kofs;
        load_lds16(Pr, ATILE(0, 0) + ldst);
        load_lds16(Kr, BTILE(0, 0) + ldst);
#pragma unroll 2
        for (int it = 0; it < 32; ++it) {
            const int cur = it & 1, k0 = it * 32;
            if (it < 31) {
                load_lds16(Pr + k0 + 32, ATILE(cur ^ 1, 0) + ldst);
                load_lds16(Kr + k0 + 32, BTILE(cur ^ 1, 0) + ldst);
                WAITV(2);
            } else {
                WAITV(0);
            }
            BARRIER();
            short8 bq0 = *(const short8*)(BTILE(cur, 0) + (wcol * 32 + l15) * 64 + rswB);
            short8 bq1 = *(const short8*)(BTILE(cur, 0) + (wcol * 32 + 16 + l15) * 64 + rswB);
#pragma unroll
            for (int m = 0; m < 4; ++m) {
                short8 am = *(const short8*)(ATILE(cur, 0) + (wrow * 64 + m * 16 + l15) * 64 + rswB);
                acc[4][m][0] = __builtin_amdgcn_mfma_f32_16x16x32_bf16(am, bq0, acc[4][m][0], 0, 0, 0);
                acc[4][m][1] = __builtin_amdgcn_mfma_f32_16x16x32_bf16(am, bq1, acc[4][m][1], 0, 0, 0);
            }
            WAITL0();
            BARRIER();
        }
    }

    // ---------------- epilogue (in-register) -------------------------------------
    const float s0 = s0p[0];
#pragma unroll
    for (int m = 0; m < 4; ++m) {
#pragma unroll
        for (int n = 0; n < 2; ++n) {
            const int v = v0 + wcol * 32 + n * 16 + l15;
            const float bi = bias[v];
            const float bff = bias[1024 + v];
            const float bc = bias[2048 + v];
            const float bo = bias[3072 + v];
            const float b2 = bias2[v];
#pragma unroll
            for (int r = 0; r < 4; ++r) {
                const int b = b0 + wrow * 64 + m * 16 + hi * 4 + r;
                const float ct = c_tm1[(size_t)b * 1024 + v];
                const float iv = sigmoidf_(acc[0][m][n][r] + bi);
                const float fv = sigmoidf_(acc[1][m][n][r] + bff);
                const float cn = fv * ct + iv * tanhf(acc[2][m][n][r] + bc);
                const float ov = sigmoidf_(acc[3][m][n][r] + bo);
                const float sk = sigmoidf_(acc[4][m][n][r] + b2);
                const float h = s0 * (ov * tanhf(cn)) + sk * (1.0f - s0);
                out_h[(size_t)b * 1024 + v] = h;
                out_c[(size_t)b * 1024 + v] = cn;
                float* ht = out_ht + (size_t)b * 4096 + v;
                ht[0] = iv;
                ht[1024] = fv;
                ht[2048] = cn;
                ht[3072] = ov;
                if (do_copy) out_prev[(size_t)b * 24576 + 23552 + v] = h;
            }
        }
    }
#undef ATILE
#undef BTILE
#undef BARRIER
#undef WAITV
#undef WAITL0
}

// ---------------- fallback shift (scratch aliased in out_prev) -------------------
__global__ __launch_bounds__(512) void shift_only(
    const float* __restrict__ prev_h, const float* __restrict__ out_h,
    const float* __restrict__ step, float* __restrict__ out_prev,
    float* __restrict__ out_step) {
    const int cb = blockIdx.x;  // 0..127
    for (int r = 0; r < 16; ++r) {
        const int b = cb * 16 + r;
        float4* d = (float4*)(out_prev + (size_t)b * 24576);
        const float4* s1 = (const float4*)(prev_h + (size_t)b * 24576 + 1024);
        const float4* s2 = (const float4*)(out_h + (size_t)b * 1024);
        for (int c = threadIdx.x; c < 6144; c += 512)
            d[c] = (c < 5888) ? s1[c] : s2[c - 5888];
    }
    if (cb == 0)
        for (int i = threadIdx.x; i < 2048; i += 512) out_step[i] = step[i] + 1.0f;
}

extern "C" void kernel_launch(void* const* d_in, const int* in_sizes, int n_in,
                              void* d_out, int out_size, void* d_ws, size_t ws_size,
                              hipStream_t stream) {
    (void)in_sizes; (void)n_in; (void)out_size;
    const float* inputs = (const float*)d_in[0];
    const float* h_tm1 = (const float*)d_in[1];
    const float* c_tm1 = (const float*)d_in[2];
    const float* step = (const float*)d_in[3];
    const float* prev_h = (const float*)d_in[4];
    const float* kernel = (const float*)d_in[5];
    const float* rkernel = (const float*)d_in[6];
    const float* kernel2 = (const float*)d_in[7];
    const float* bias = (const float*)d_in[8];
    const float* bias2 = (const float*)d_in[9];
    const float* s0 = (const float*)d_in[10];

    float* out = (float*)d_out;
    float* out_h = out;                // [B,U]
    float* out_ht = out + 2097152;     // [B,4U]
    float* out_c = out + 10485760;     // [B,U]
    float* out_step = out + 12582912;  // [B,1]
    float* out_prev = out + 12584960;  // [B,U*SKIP]

    const size_t NEED = 44040192;  // 42 MB of bf16 scratch
    const int fits = (ws_size >= NEED);
    char* scr = fits ? (char*)d_ws : (char*)out_prev;
    __hip_bfloat16* kt = (__hip_bfloat16*)(scr + 0);             // [4096][1024]
    __hip_bfloat16* rkt = (__hip_bfloat16*)(scr + 8388608);      // [4096][1024]
    __hip_bfloat16* k2t = (__hip_bfloat16*)(scr + 16777216);     // [1024][1024]
    __hip_bfloat16* xin = (__hip_bfloat16*)(scr + 18874368);     // [2048][1024]
    __hip_bfloat16* hb = (__hip_bfloat16*)(scr + 23068672);      // [2048][4096]
    __hip_bfloat16* ph0 = (__hip_bfloat16*)(scr + 39845888);     // [2048][1024]

    prep<<<21504, 256, 0, stream>>>(inputs, h_tm1, prev_h, kernel, rkernel, kernel2,
                                    kt, rkt, k2t, xin, hb, ph0);
    if (fits) {
        mega<<<256, 512, 0, stream>>>(xin, hb, ph0, kt, rkt, k2t, c_tm1, bias, bias2,
                                      s0, prev_h, step, out_h, out_ht, out_c,
                                      out_step, out_prev, 1);
    } else {
        mega<<<128, 512, 0, stream>>>(xin, hb, ph0, kt, rkt, k2t, c_tm1, bias, bias2,
                                      s0, prev_h, step, out_h, out_ht, out_c,
                                      out_step, out_prev, 0);
        shift_only<<<128, 512, 0, stream>>>(prev_h, out_h, step, out_prev, out_step);
    }
}